// Round 3
// baseline (111.627 us; speedup 1.0000x reference)
//
#include <hip/hip_runtime.h>
#include <hip/hip_bf16.h>
#include <stdint.h>

// Problem constants (from reference setup_inputs)
constexpr int cB  = 8;
constexpr int cC  = 256;
constexpr int cHW = 128 * 128;   // 16384
constexpr int cN  = 100;
constexpr int cT  = 6;
constexpr int NPAD = 112;        // cN padded to multiple of 16
constexpr int CH  = 128;         // channels per pool block (C split in 2)
constexpr int KC  = 512;         // pixels per pool block
constexpr int KS  = 64;          // pixels per LDS subtile
constexpr int NSUB = KC / KS;    // 8
constexpr int KCHUNKS = cHW / KC; // 32
constexpr int WPB = cHW / 32;    // 512 bit-words per (b,n) row

typedef __attribute__((ext_vector_type(8))) short short8;
typedef __attribute__((ext_vector_type(4))) float floatx4;

__device__ __forceinline__ unsigned short f2bf(float f) {
    union { float f; unsigned u; } v; v.f = f;
    unsigned u = v.u;
    unsigned r = u + 0x7fffu + ((u >> 16) & 1u);   // RNE
    return (unsigned short)(r >> 16);
}
__device__ __forceinline__ unsigned pack2(float a, float b) {
    return (unsigned)f2bf(a) | ((unsigned)f2bf(b) << 16);
}

// ---------------------------------------------------------------------------
// K0: binarize masks -> bit-pack [b][n(112)][word(512)] + exact msum per row.
// grid = cB * NPAD blocks x 256 threads. n>=100 rows are zero-filled (pad).
// ---------------------------------------------------------------------------
__global__ __launch_bounds__(256)
void mask_prep_kernel(const float* __restrict__ masks,
                      unsigned* __restrict__ bits, unsigned* __restrict__ msum)
{
    const int t = threadIdx.x;
    const int b = blockIdx.x / NPAD;
    const int n = blockIdx.x % NPAD;
    unsigned* dst = bits + ((size_t)b * NPAD + n) * WPB;

    if (n >= cN) {                       // zero pad rows
        dst[t] = 0; dst[t + 256] = 0;
        return;
    }
    const float* mrow = masks + ((size_t)b * cN + n) * cHW;
    int pc = 0;
    #pragma unroll
    for (int r = 0; r < 2; ++r) {
        unsigned w = 0;
        #pragma unroll
        for (int jj = 0; jj < 8; ++jj) {
            const floatx4 v = *(const floatx4*)(mrow + r * 8192 + t * 32 + jj * 4);
            w |= (v.x > 0.5f ? 1u : 0u) << (jj * 4 + 0);
            w |= (v.y > 0.5f ? 1u : 0u) << (jj * 4 + 1);
            w |= (v.z > 0.5f ? 1u : 0u) << (jj * 4 + 2);
            w |= (v.w > 0.5f ? 1u : 0u) << (jj * 4 + 3);
        }
        dst[r * 256 + t] = w;            // word index = r*256 + t (coalesced)
        pc += __popc(w);
    }
    // block reduce popcount
    #pragma unroll
    for (int off = 32; off > 0; off >>= 1) pc += __shfl_xor(pc, off, 64);
    __shared__ int ps[4];
    if ((t & 63) == 0) ps[t >> 6] = pc;
    __syncthreads();
    if (t == 0) msum[b * cN + n] = (unsigned)(ps[0] + ps[1] + ps[2] + ps[3]);
}

// ---------------------------------------------------------------------------
// K1: pooling GEMM, software-pipelined.
// grid = KCHUNKS*cB*2 (512 wgs), block = 512 (8 waves).
// bid = k*16 + b*2 + ch.  A = mask bits (reg-expanded via LDS nibble LUT),
// B = vf fp32 -> bf16, double-buffered LDS, loads issued 2 subtiles ahead.
// ---------------------------------------------------------------------------
template<bool USE_PART>
__global__ __launch_bounds__(512, 4)
void pool_kernel(const float* __restrict__ vf, const unsigned* __restrict__ bits,
                 float* __restrict__ part, float* __restrict__ pooled)
{
    __shared__ uint2 lutLDS[16];
    __shared__ __align__(16) char Bt[2 * CH * (KS * 2)];   // 2 x 128 rows x 128 B

    const int tid  = threadIdx.x;
    const int lane = tid & 63;
    const int w    = tid >> 6;               // wave 0..7
    const int bid  = blockIdx.x;
    const int k    = bid >> 4;               // 0..31
    const int b    = (bid >> 1) & 7;
    const int ch   = bid & 1;
    const int p0   = k * KC;

    const int l15 = lane & 15;
    const int lk  = lane >> 4;               // 0..3
    const int shl = lk * 8;
    const int crow = w * 16 + l15;           // wave's c column within CH

    // staging role: row cst (0..127), lane-group j4 (0..3)
    const int cst = tid >> 2;
    const int j4  = tid & 3;

    if (tid < 16) {
        unsigned n0 = (tid & 1) ? 0x3F80u : 0u;
        unsigned n1 = (tid & 2) ? 0x3F80u : 0u;
        unsigned n2 = (tid & 4) ? 0x3F80u : 0u;
        unsigned n3 = (tid & 8) ? 0x3F80u : 0u;
        lutLDS[tid] = make_uint2(n0 | (n1 << 16), n2 | (n3 << 16));
    }

    const float* vsrc = vf + ((size_t)b * cC + ch * CH) * cHW + p0;
    const unsigned* bitbase = bits + (size_t)b * NPAD * WPB + (p0 >> 5);

    floatx4 acc[7];
    #pragma unroll
    for (int mt = 0; mt < 7; ++mt) acc[mt] = (floatx4){0.f, 0.f, 0.f, 0.f};

    // ---- prologue: stage s=0 into buf0, issue loads for s=1
    floatx4 vr[4];
    #pragma unroll
    for (int i = 0; i < 4; ++i)
        vr[i] = *(const floatx4*)(vsrc + (size_t)cst * cHW + 0 * KS + (j4 + i * 4) * 4);
    #pragma unroll
    for (int i = 0; i < 4; ++i) {
        const int q = j4 + i * 4;
        uint2 wv; wv.x = pack2(vr[i].x, vr[i].y); wv.y = pack2(vr[i].z, vr[i].w);
        *(uint2*)(Bt + cst * 128 + ((((q >> 1) ^ (cst & 7)) << 4) + (q & 1) * 8)) = wv;
    }
    #pragma unroll
    for (int i = 0; i < 4; ++i)
        vr[i] = *(const floatx4*)(vsrc + (size_t)cst * cHW + 1 * KS + (j4 + i * 4) * 4);
    __syncthreads();

    int cur = 0;
    for (int s = 0; s < NSUB; ++s) {
        // prefetch this subtile's mask bits (L1/L2-resident)
        unsigned bw[2][7];
        #pragma unroll
        for (int ks = 0; ks < 2; ++ks)
            #pragma unroll
            for (int mt = 0; mt < 7; ++mt)
                bw[ks][mt] = bitbase[(size_t)(mt * 16 + l15) * WPB + s * 2 + ks];

        // compute on buf[cur]
        #pragma unroll
        for (int ks = 0; ks < 2; ++ks) {
            const int pos = ((ks * 4 + lk) ^ (crow & 7)) << 4;
            const short8 bfr = *(const short8*)(Bt + cur * 16384 + crow * 128 + pos);
            #pragma unroll
            for (int mt = 0; mt < 7; ++mt) {
                const unsigned byte = (bw[ks][mt] >> shl) & 0xFFu;
                const uint2 lo = lutLDS[byte & 15u];
                const uint2 hi = lutLDS[byte >> 4];
                union { short8 s8; uint4 u4; } a;
                a.u4 = (uint4){lo.x, lo.y, hi.x, hi.y};
                acc[mt] = __builtin_amdgcn_mfma_f32_16x16x32_bf16(a.s8, bfr, acc[mt], 0, 0, 0);
            }
        }

        // stage next: convert in-flight regs (s+1) into buf[cur^1], issue s+2
        if (s + 1 < NSUB) {
            #pragma unroll
            for (int i = 0; i < 4; ++i) {
                const int q = j4 + i * 4;
                uint2 wv; wv.x = pack2(vr[i].x, vr[i].y); wv.y = pack2(vr[i].z, vr[i].w);
                *(uint2*)(Bt + (cur ^ 1) * 16384 + cst * 128 +
                          ((((q >> 1) ^ (cst & 7)) << 4) + (q & 1) * 8)) = wv;
            }
            if (s + 2 < NSUB) {
                #pragma unroll
                for (int i = 0; i < 4; ++i)
                    vr[i] = *(const floatx4*)(vsrc + (size_t)cst * cHW + (s + 2) * KS + (j4 + i * 4) * 4);
            }
        }
        __syncthreads();
        cur ^= 1;
    }

    // ---- write partials: C/D layout col=l15 (c), row=lk*4+i (n)
    if (USE_PART) {
        float* dst = part + (size_t)bid * (cN * CH);
        #pragma unroll
        for (int mt = 0; mt < 7; ++mt) {
            #pragma unroll
            for (int i = 0; i < 4; ++i) {
                const int n = mt * 16 + lk * 4 + i;
                if (n < cN) dst[n * CH + crow] = acc[mt][i];
            }
        }
    } else {
        #pragma unroll
        for (int mt = 0; mt < 7; ++mt) {
            #pragma unroll
            for (int i = 0; i < 4; ++i) {
                const int n = mt * 16 + lk * 4 + i;
                if (n < cN)
                    atomicAdd(&pooled[((size_t)b * cN + n) * cC + ch * CH + crow], acc[mt][i]);
            }
        }
    }
}

// ---------------------------------------------------------------------------
// K2: reduce partials + per (b,n) row -> normalize, sims, CE, masked sum
// ---------------------------------------------------------------------------
__device__ __forceinline__ float wred(float v) {
    #pragma unroll
    for (int off = 32; off > 0; off >>= 1) v += __shfl_xor(v, off, 64);
    return v;
}

template<bool USE_PART>
__global__ __launch_bounds__(256)
void finalize_kernel(const float* __restrict__ pp, const unsigned* __restrict__ msum,
                     const float* __restrict__ text, const int* __restrict__ labels,
                     const float* __restrict__ temp, float* __restrict__ sums)
{
    const int lane = threadIdx.x & 63;
    const int row  = blockIdx.x * 4 + (threadIdx.x >> 6);
    if (row >= cB * cN) return;
    const int b = row / cN, n = row % cN;
    const int ch = lane >> 5;
    const int cb = (lane & 31) * 4;
    const int c_global = ch * CH + cb;

    floatx4 p = (floatx4){0.f, 0.f, 0.f, 0.f};
    if (USE_PART) {
        const float* src = pp + (size_t)(b * 2 + ch) * (cN * CH) + n * CH + cb;
        #pragma unroll
        for (int kk = 0; kk < KCHUNKS; ++kk)
            p += *(const floatx4*)(src + (size_t)kk * 16 * (cN * CH));
    } else {
        p = *(const floatx4*)(pp + (size_t)row * cC + c_global);
    }

    const float m   = (float)msum[row];
    const float inv = 1.0f / fmaxf(m, 1.0f);
    p.x *= inv; p.y *= inv; p.z *= inv; p.w *= inv;

    float psq = p.x * p.x + p.y * p.y + p.z * p.z + p.w * p.w;
    float dot[cT], tsq[cT];
    #pragma unroll
    for (int t = 0; t < cT; ++t) {
        const floatx4 x = *(const floatx4*)(text + (size_t)t * cC + c_global);
        dot[t] = p.x * x.x + p.y * x.y + p.z * x.z + p.w * x.w;
        tsq[t] = x.x * x.x + x.y * x.y + x.z * x.z + x.w * x.w;
    }
    psq = wred(psq);
    #pragma unroll
    for (int t = 0; t < cT; ++t) { dot[t] = wred(dot[t]); tsq[t] = wred(tsq[t]); }

    if (lane == 0) {
        const float tempv = fabsf(temp[0]);
        const float pn = fmaxf(sqrtf(psq), 1e-12f);
        float sims[cT], mx = -1e30f;
        #pragma unroll
        for (int t = 0; t < cT; ++t) {
            sims[t] = dot[t] / (pn * fmaxf(sqrtf(tsq[t]), 1e-12f)) / tempv;
            mx = fmaxf(mx, sims[t]);
        }
        float se = 0.f;
        #pragma unroll
        for (int t = 0; t < cT; ++t) se += expf(sims[t] - mx);
        const float lse = logf(se);

        const int lab = labels[row];
        const int tgt = min(max(lab - 1, 0), cT - 1);
        const float ce = -(sims[tgt] - mx - lse);
        const bool valid = (lab >= 1) && (lab <= cT) && (m >= 1.0f);
        if (valid) {
            atomicAdd(&sums[0], ce);
            atomicAdd(&sums[1], 1.0f);
        }
    }
}

__global__ void loss_kernel(const float* __restrict__ sums, float* __restrict__ out) {
    const float s = sums[0], c = sums[1];
    out[0] = (c > 0.f) ? s / fmaxf(c, 1.f) : 0.f;
}

// ---------------------------------------------------------------------------
extern "C" void kernel_launch(void* const* d_in, const int* in_sizes, int n_in,
                              void* d_out, int out_size, void* d_ws, size_t ws_size,
                              hipStream_t stream)
{
    const float* vf     = (const float*)d_in[0];
    const float* text   = (const float*)d_in[1];
    const float* masks  = (const float*)d_in[2];
    const int*   labels = (const int*)d_in[3];
    const float* temp   = (const float*)d_in[4];

    float*    wsf  = (float*)d_ws;
    float*    sums = wsf;                    // [0]=sum(ce*valid), [1]=cnt
    unsigned* msum = (unsigned*)(wsf + 8);   // 800 u32

    const size_t PART_FLOATS = (size_t)KCHUNKS * cB * 2 * cN * CH;  // 6.55M
    const size_t BITS_WORDS  = (size_t)cB * NPAD * WPB;             // 458752

    const bool use_part =
        ws_size >= (4096 + PART_FLOATS + BITS_WORDS) * sizeof(float);

    if (use_part) {
        float*    part = wsf + 4096;
        unsigned* bits = (unsigned*)(wsf + 4096 + PART_FLOATS);
        hipMemsetAsync(d_ws, 0, 4096 * sizeof(float), stream);  // sums (+slack)
        hipLaunchKernelGGL(mask_prep_kernel, dim3(cB * NPAD), dim3(256), 0, stream,
                           masks, bits, msum);
        hipLaunchKernelGGL((pool_kernel<true>), dim3(KCHUNKS * cB * 2), dim3(512), 0, stream,
                           vf, bits, part, nullptr);
        hipLaunchKernelGGL((finalize_kernel<true>), dim3((cB * cN + 3) / 4), dim3(256), 0, stream,
                           part, msum, text, labels, temp, sums);
    } else {
        float*    pooled = wsf + 1024;                         // 800*256
        unsigned* bits   = (unsigned*)(wsf + 1024 + (size_t)cB * cN * cC);
        hipMemsetAsync(d_ws, 0, (1024 + (size_t)cB * cN * cC) * sizeof(float), stream);
        hipLaunchKernelGGL(mask_prep_kernel, dim3(cB * NPAD), dim3(256), 0, stream,
                           masks, bits, msum);
        hipLaunchKernelGGL((pool_kernel<false>), dim3(KCHUNKS * cB * 2), dim3(512), 0, stream,
                           vf, bits, nullptr, pooled);
        hipLaunchKernelGGL((finalize_kernel<false>), dim3((cB * cN + 3) / 4), dim3(256), 0, stream,
                           pooled, msum, text, labels, temp, sums);
    }
    hipLaunchKernelGGL(loss_kernel, dim3(1), dim3(1), 0, stream,
                       sums, (float*)d_out);
}

// Round 4
// 81.014 us; speedup vs baseline: 1.3779x; 1.3779x over previous
//
#include <hip/hip_runtime.h>
#include <hip/hip_bf16.h>
#include <stdint.h>

// Problem constants (from reference setup_inputs)
constexpr int cB  = 8;
constexpr int cC  = 256;
constexpr int cHW = 128 * 128;   // 16384
constexpr int cN  = 100;
constexpr int cT  = 6;
constexpr int NPAD = 112;        // cN padded to multiple of 16
constexpr int WPB = cHW / 32;    // 512 bit-words per (b,n) row
constexpr int KSLICES = 16;      // k-slices per (b, c-tile)
constexpr int PXS = cHW / KSLICES;  // 1024 px per wave
constexpr int NWIN = PXS / 32;      // 32 windows of 32 px
constexpr int NWAVES = cB * 16 * KSLICES;  // 2048 waves

typedef __attribute__((ext_vector_type(8))) short short8;
typedef __attribute__((ext_vector_type(4))) float floatx4;

// ---------------------------------------------------------------------------
// K0: binarize masks -> bit-pack [b][n(112)][word(512)] + exact msum per row.
// Bit order within a 32-px word (co-designed with pool's bfe expansion):
//   px offset o = lambda*4 + c  <->  bit position = c*8 + lambda
// grid = cB*NPAD blocks x 256 threads (4 waves; wave w owns px [w*4096,+4096))
// ---------------------------------------------------------------------------
__global__ __launch_bounds__(256)
void mask_prep_kernel(const float* __restrict__ masks,
                      unsigned* __restrict__ bits, unsigned* __restrict__ msum)
{
    const int t = threadIdx.x, lane = t & 63, w = t >> 6;
    const int b = blockIdx.x / NPAD;
    const int n = blockIdx.x % NPAD;
    unsigned* dst = bits + ((size_t)b * NPAD + n) * WPB;

    if (n >= cN) {                       // zero pad rows
        *(uint2*)(dst + t * 2) = make_uint2(0u, 0u);
        return;
    }
    const float* src = masks + ((size_t)b * cN + n) * cHW + w * 4096;
    unsigned* wdst = dst + w * 128;
    int pc = 0;
    for (int r = 0; r < 16; ++r) {
        const floatx4 v = *(const floatx4*)(src + r * 256 + lane * 4);
        const bool b0 = v.x > 0.5f, b1 = v.y > 0.5f, b2 = v.z > 0.5f, b3 = v.w > 0.5f;
        const unsigned long long B0 = __ballot(b0), B1 = __ballot(b1),
                                 B2 = __ballot(b2), B3 = __ballot(b3);
        pc += (int)b0 + (int)b1 + (int)b2 + (int)b3;
        if (lane < 8) {
            const int sh = lane * 8;
            const unsigned word =
                  (unsigned)((B0 >> sh) & 0xFFull)
                | ((unsigned)((B1 >> sh) & 0xFFull) << 8)
                | ((unsigned)((B2 >> sh) & 0xFFull) << 16)
                | ((unsigned)((B3 >> sh) & 0xFFull) << 24);
            wdst[r * 8 + lane] = word;
        }
    }
    #pragma unroll
    for (int off = 32; off > 0; off >>= 1) pc += __shfl_xor(pc, off, 64);
    __shared__ int ps[4];
    if (lane == 0) ps[w] = pc;
    __syncthreads();
    if (t == 0) msum[b * cN + n] = (unsigned)(ps[0] + ps[1] + ps[2] + ps[3]);
}

// ---------------------------------------------------------------------------
// K1: pooling via MFMA, zero LDS, zero barriers, 2048 independent waves.
// wave gw = b*256 + ct*16 + ks: owns (b, c-cols [ct*16,+16), px [ks*1024,+1024))
// A = mask bits (bfe-expanded to bf16 0/1), B = vf fp32 -> bf16 via v_perm RTZ.
// ---------------------------------------------------------------------------
template<bool USE_PART>
__global__ __launch_bounds__(256)
void pool_kernel(const float* __restrict__ vf, const unsigned* __restrict__ bits,
                 float* __restrict__ part, float* __restrict__ pooled)
{
    const int tid  = threadIdx.x;
    const int lane = tid & 63;
    const int gw   = blockIdx.x * 4 + (tid >> 6);
    const int b    = gw >> 8;
    const int ct   = (gw >> 4) & 15;
    const int ks   = gw & 15;
    const int l15  = lane & 15;
    const int lk   = lane >> 4;          // 0..3
    const int lk2  = lk * 2;             // bit-offset base for bfe expansion
    const int p0   = ks * PXS;

    const float* vrow = vf + ((size_t)(b * cC + ct * 16 + l15)) * cHW + p0 + lk * 8;
    const unsigned* brow = bits + ((size_t)b * NPAD + l15) * WPB + (p0 >> 5);

    floatx4 acc[7];
    #pragma unroll
    for (int mt = 0; mt < 7; ++mt) acc[mt] = (floatx4){0.f, 0.f, 0.f, 0.f};

    // B prefetch: depth 4 windows, 2 float4 each
    floatx4 vr[4][2];
    #pragma unroll
    for (int u = 0; u < 4; ++u) {
        vr[u][0] = *(const floatx4*)(vrow + u * 32);
        vr[u][1] = *(const floatx4*)(vrow + u * 32 + 4);
    }
    // bits double-buffer: one uint4 (4 windows) per n-tile row
    uint4 bwA[7], bwB[7];
    #pragma unroll
    for (int mt = 0; mt < 7; ++mt)
        bwA[mt] = *(const uint4*)(brow + (size_t)mt * 16 * WPB);

    auto GROUP = [&](int g, uint4 (&bw)[7], uint4 (&bwn)[7]) {
        if (g < 7) {
            #pragma unroll
            for (int mt = 0; mt < 7; ++mt)
                bwn[mt] = *(const uint4*)(brow + (size_t)mt * 16 * WPB + (g + 1) * 4);
        }
        #pragma unroll
        for (int u = 0; u < 4; ++u) {
            const int w = g * 4 + u;
            // ---- B fragment: 8 fp32 -> 8 bf16 (RTZ via v_perm)
            union { short8 s8; uint4 u4; } bq;
            bq.u4.x = __builtin_amdgcn_perm(__builtin_bit_cast(unsigned, vr[u][0].y),
                                            __builtin_bit_cast(unsigned, vr[u][0].x), 0x07060302u);
            bq.u4.y = __builtin_amdgcn_perm(__builtin_bit_cast(unsigned, vr[u][0].w),
                                            __builtin_bit_cast(unsigned, vr[u][0].z), 0x07060302u);
            bq.u4.z = __builtin_amdgcn_perm(__builtin_bit_cast(unsigned, vr[u][1].y),
                                            __builtin_bit_cast(unsigned, vr[u][1].x), 0x07060302u);
            bq.u4.w = __builtin_amdgcn_perm(__builtin_bit_cast(unsigned, vr[u][1].w),
                                            __builtin_bit_cast(unsigned, vr[u][1].z), 0x07060302u);
            // ---- issue B loads for window w+4
            if (g < 7) {
                vr[u][0] = *(const floatx4*)(vrow + (w + 4) * 32);
                vr[u][1] = *(const floatx4*)(vrow + (w + 4) * 32 + 4);
            }
            // ---- A expand + MFMA per n-tile
            #pragma unroll
            for (int mt = 0; mt < 7; ++mt) {
                const unsigned word = (u == 0) ? bw[mt].x : (u == 1) ? bw[mt].y
                                    : (u == 2) ? bw[mt].z : bw[mt].w;
                // frag element j <-> bit (j&3)*8 + lk*2 + (j>>2)
                union { short8 s8; uint4 u4; } aq;
                aq.u4.x = ((unsigned)__builtin_amdgcn_sbfe(word, lk2 + 0,  1) & 0x3F80u)
                        | ((unsigned)__builtin_amdgcn_sbfe(word, lk2 + 8,  1) & 0x3F800000u);
                aq.u4.y = ((unsigned)__builtin_amdgcn_sbfe(word, lk2 + 16, 1) & 0x3F80u)
                        | ((unsigned)__builtin_amdgcn_sbfe(word, lk2 + 24, 1) & 0x3F800000u);
                aq.u4.z = ((unsigned)__builtin_amdgcn_sbfe(word, lk2 + 1,  1) & 0x3F80u)
                        | ((unsigned)__builtin_amdgcn_sbfe(word, lk2 + 9,  1) & 0x3F800000u);
                aq.u4.w = ((unsigned)__builtin_amdgcn_sbfe(word, lk2 + 17, 1) & 0x3F80u)
                        | ((unsigned)__builtin_amdgcn_sbfe(word, lk2 + 25, 1) & 0x3F800000u);
                acc[mt] = __builtin_amdgcn_mfma_f32_16x16x32_bf16(aq.s8, bq.s8, acc[mt], 0, 0, 0);
            }
        }
    };

    for (int gp = 0; gp < 4; ++gp) {
        GROUP(2 * gp,     bwA, bwB);
        GROUP(2 * gp + 1, bwB, bwA);
    }

    // ---- write partials: C/D layout col=l15 (c within tile), row=lk*4+i (n)
    if (USE_PART) {
        float* dst = part + (size_t)gw * (cN * 16);
        #pragma unroll
        for (int mt = 0; mt < 7; ++mt) {
            #pragma unroll
            for (int i = 0; i < 4; ++i) {
                const int n = mt * 16 + lk * 4 + i;
                if (n < cN) dst[n * 16 + l15] = acc[mt][i];
            }
        }
    } else {
        #pragma unroll
        for (int mt = 0; mt < 7; ++mt) {
            #pragma unroll
            for (int i = 0; i < 4; ++i) {
                const int n = mt * 16 + lk * 4 + i;
                if (n < cN)
                    atomicAdd(&pooled[((size_t)b * cN + n) * cC + ct * 16 + l15], acc[mt][i]);
            }
        }
    }
}

// ---------------------------------------------------------------------------
// K2: reduce partials + per (b,n) row -> normalize, sims, CE, masked sum
// ---------------------------------------------------------------------------
__device__ __forceinline__ float wred(float v) {
    #pragma unroll
    for (int off = 32; off > 0; off >>= 1) v += __shfl_xor(v, off, 64);
    return v;
}

template<bool USE_PART>
__global__ __launch_bounds__(256)
void finalize_kernel(const float* __restrict__ pp, const unsigned* __restrict__ msum,
                     const float* __restrict__ text, const int* __restrict__ labels,
                     const float* __restrict__ temp, float* __restrict__ sums)
{
    const int lane = threadIdx.x & 63;
    const int row  = blockIdx.x * 4 + (threadIdx.x >> 6);
    if (row >= cB * cN) return;
    const int b = row / cN, n = row % cN;

    floatx4 p = (floatx4){0.f, 0.f, 0.f, 0.f};
    if (USE_PART) {
        const int ct  = lane >> 2;
        const int col = (lane & 3) * 4;
        const float* src = pp + ((size_t)(b * 256 + ct * 16)) * (cN * 16) + n * 16 + col;
        #pragma unroll
        for (int kk = 0; kk < KSLICES; ++kk)
            p += *(const floatx4*)(src + (size_t)kk * (cN * 16));
    } else {
        p = *(const floatx4*)(pp + (size_t)row * cC + lane * 4);
    }

    const float m   = (float)msum[row];
    const float inv = 1.0f / fmaxf(m, 1.0f);
    p.x *= inv; p.y *= inv; p.z *= inv; p.w *= inv;

    // c order differs between paths, but all reductions below are c-order-invariant
    const int c_global = USE_PART ? ((lane >> 2) * 16 + (lane & 3) * 4) : lane * 4;

    float psq = p.x * p.x + p.y * p.y + p.z * p.z + p.w * p.w;
    float dot[cT], tsq[cT];
    #pragma unroll
    for (int t = 0; t < cT; ++t) {
        const floatx4 x = *(const floatx4*)(text + (size_t)t * cC + c_global);
        dot[t] = p.x * x.x + p.y * x.y + p.z * x.z + p.w * x.w;
        tsq[t] = x.x * x.x + x.y * x.y + x.z * x.z + x.w * x.w;
    }
    psq = wred(psq);
    #pragma unroll
    for (int t = 0; t < cT; ++t) { dot[t] = wred(dot[t]); tsq[t] = wred(tsq[t]); }

    if (lane == 0) {
        const float tempv = fabsf(temp[0]);
        const float pn = fmaxf(sqrtf(psq), 1e-12f);
        float sims[cT], mx = -1e30f;
        #pragma unroll
        for (int t = 0; t < cT; ++t) {
            sims[t] = dot[t] / (pn * fmaxf(sqrtf(tsq[t]), 1e-12f)) / tempv;
            mx = fmaxf(mx, sims[t]);
        }
        float se = 0.f;
        #pragma unroll
        for (int t = 0; t < cT; ++t) se += expf(sims[t] - mx);
        const float lse = logf(se);

        const int lab = labels[row];
        const int tgt = min(max(lab - 1, 0), cT - 1);
        const float ce = -(sims[tgt] - mx - lse);
        const bool valid = (lab >= 1) && (lab <= cT) && (m >= 1.0f);
        if (valid) {
            atomicAdd(&sums[0], ce);
            atomicAdd(&sums[1], 1.0f);
        }
    }
}

__global__ void loss_kernel(const float* __restrict__ sums, float* __restrict__ out) {
    const float s = sums[0], c = sums[1];
    out[0] = (c > 0.f) ? s / fmaxf(c, 1.f) : 0.f;
}

// ---------------------------------------------------------------------------
extern "C" void kernel_launch(void* const* d_in, const int* in_sizes, int n_in,
                              void* d_out, int out_size, void* d_ws, size_t ws_size,
                              hipStream_t stream)
{
    const float* vf     = (const float*)d_in[0];
    const float* text   = (const float*)d_in[1];
    const float* masks  = (const float*)d_in[2];
    const int*   labels = (const int*)d_in[3];
    const float* temp   = (const float*)d_in[4];

    float*    wsf  = (float*)d_ws;
    float*    sums = wsf;                    // [0]=sum(ce*valid), [1]=cnt
    unsigned* msum = (unsigned*)(wsf + 8);   // 800 u32

    const size_t PART_FLOATS = (size_t)NWAVES * cN * 16;    // 3,276,800 (13.1 MB)
    const size_t BITS_WORDS  = (size_t)cB * NPAD * WPB;     // 458,752  (1.8 MB)

    const bool use_part =
        ws_size >= (4096 + PART_FLOATS + BITS_WORDS + 64) * sizeof(float) / 1;  // ~15 MB

    if (use_part) {
        float*    part = wsf + 4096;
        unsigned* bits = (unsigned*)(wsf + 4096 + PART_FLOATS);
        hipMemsetAsync(d_ws, 0, 4096 * sizeof(float), stream);  // sums (+slack)
        hipLaunchKernelGGL(mask_prep_kernel, dim3(cB * NPAD), dim3(256), 0, stream,
                           masks, bits, msum);
        hipLaunchKernelGGL((pool_kernel<true>), dim3(NWAVES / 4), dim3(256), 0, stream,
                           vf, bits, part, nullptr);
        hipLaunchKernelGGL((finalize_kernel<true>), dim3((cB * cN + 3) / 4), dim3(256), 0, stream,
                           part, msum, text, labels, temp, sums);
    } else {
        float*    pooled = wsf + 1024;                          // 800*256 fp32
        unsigned* bits   = (unsigned*)(wsf + 1024 + (size_t)cB * cN * cC);
        hipMemsetAsync(d_ws, 0, (1024 + (size_t)cB * cN * cC) * sizeof(float), stream);
        hipLaunchKernelGGL(mask_prep_kernel, dim3(cB * NPAD), dim3(256), 0, stream,
                           masks, bits, msum);
        hipLaunchKernelGGL((pool_kernel<false>), dim3(NWAVES / 4), dim3(256), 0, stream,
                           vf, bits, nullptr, pooled);
        hipLaunchKernelGGL((finalize_kernel<false>), dim3((cB * cN + 3) / 4), dim3(256), 0, stream,
                           pooled, msum, text, labels, temp, sums);
    }
    hipLaunchKernelGGL(loss_kernel, dim3(1), dim3(1), 0, stream,
                       sums, (float*)d_out);
}

// Round 5
// 57.300 us; speedup vs baseline: 1.9481x; 1.4139x over previous
//
#include <hip/hip_runtime.h>
#include <hip/hip_bf16.h>
#include <stdint.h>

// Problem constants (from reference setup_inputs)
constexpr int cB  = 8;
constexpr int cC  = 256;
constexpr int cHW = 128 * 128;   // 16384
constexpr int cN  = 100;
constexpr int cT  = 6;
constexpr int NPAD = 112;        // cN padded to multiple of 16
constexpr int WPB = cHW / 32;    // 512 bit-words per (b,n) row
constexpr int KSLICES = 16;      // k-slices per (b, c-tile)
constexpr int PXS = cHW / KSLICES;  // 1024 px per wave
constexpr int NWAVES = cB * 16 * KSLICES;  // 2048 waves

typedef __attribute__((ext_vector_type(8))) short short8;
typedef __attribute__((ext_vector_type(4))) float floatx4;

// RNE fp32 pair -> packed bf16x2 (compiler emits v_cvt_pk_bf16_f32 on gfx950)
__device__ __forceinline__ unsigned pack2(float a, float b) {
    const __hip_bfloat16 ha = __float2bfloat16(a);
    const __hip_bfloat16 hb = __float2bfloat16(b);
    return (unsigned)__builtin_bit_cast(unsigned short, ha)
         | ((unsigned)__builtin_bit_cast(unsigned short, hb) << 16);
}

// ---------------------------------------------------------------------------
// K0: binarize masks -> bit-pack [b][n(112)][word(512)] + exact msum per row.
// Bit order within a 32-px word: px offset o = lambda*4 + c <-> bit c*8+lambda
// grid = cB*NPAD blocks x 256 threads (4 waves; wave w owns px [w*4096,+4096))
// ---------------------------------------------------------------------------
__global__ __launch_bounds__(256)
void mask_prep_kernel(const float* __restrict__ masks,
                      unsigned* __restrict__ bits, unsigned* __restrict__ msum)
{
    const int t = threadIdx.x, lane = t & 63, w = t >> 6;
    const int b = blockIdx.x / NPAD;
    const int n = blockIdx.x % NPAD;
    unsigned* dst = bits + ((size_t)b * NPAD + n) * WPB;

    if (n >= cN) {                       // zero pad rows
        *(uint2*)(dst + t * 2) = make_uint2(0u, 0u);
        return;
    }
    const float* src = masks + ((size_t)b * cN + n) * cHW + w * 4096;
    unsigned* wdst = dst + w * 128;
    int pc = 0;
    for (int r = 0; r < 16; ++r) {
        const floatx4 v = *(const floatx4*)(src + r * 256 + lane * 4);
        const bool b0 = v.x > 0.5f, b1 = v.y > 0.5f, b2 = v.z > 0.5f, b3 = v.w > 0.5f;
        const unsigned long long B0 = __ballot(b0), B1 = __ballot(b1),
                                 B2 = __ballot(b2), B3 = __ballot(b3);
        pc += (int)b0 + (int)b1 + (int)b2 + (int)b3;
        if (lane < 8) {
            const int sh = lane * 8;
            const unsigned word =
                  (unsigned)((B0 >> sh) & 0xFFull)
                | ((unsigned)((B1 >> sh) & 0xFFull) << 8)
                | ((unsigned)((B2 >> sh) & 0xFFull) << 16)
                | ((unsigned)((B3 >> sh) & 0xFFull) << 24);
            wdst[r * 8 + lane] = word;
        }
    }
    #pragma unroll
    for (int off = 32; off > 0; off >>= 1) pc += __shfl_xor(pc, off, 64);
    __shared__ int ps[4];
    if (lane == 0) ps[w] = pc;
    __syncthreads();
    if (t == 0) msum[b * cN + n] = (unsigned)(ps[0] + ps[1] + ps[2] + ps[3]);
}

// ---------------------------------------------------------------------------
// K1: pooling via MFMA, zero LDS, zero barriers, 2048 independent waves.
// wave gw = b*256 + ct*16 + ks: owns (b, c-cols [ct*16,+16), px [ks*1024,+1024))
// A = mask bits (perm+umul24-expanded to bf16 0/1), B = vf fp32 -> bf16 RNE.
// ---------------------------------------------------------------------------
template<bool USE_PART>
__global__ __launch_bounds__(256)
void pool_kernel(const float* __restrict__ vf, const unsigned* __restrict__ bits,
                 float* __restrict__ part, float* __restrict__ pooled)
{
    const int tid  = threadIdx.x;
    const int lane = tid & 63;
    const int gw   = blockIdx.x * 4 + (tid >> 6);
    const int b    = gw >> 8;
    const int ct   = (gw >> 4) & 15;
    const int ks   = gw & 15;
    const int l15  = lane & 15;
    const int lk   = lane >> 4;          // 0..3
    const int lk2  = lk * 2;             // bit-offset base for expansion
    const int p0   = ks * PXS;

    const float* vrow = vf + ((size_t)(b * cC + ct * 16 + l15)) * cHW + p0 + lk * 8;
    const unsigned* brow = bits + ((size_t)b * NPAD + l15) * WPB + (p0 >> 5);

    floatx4 acc[7];
    #pragma unroll
    for (int mt = 0; mt < 7; ++mt) acc[mt] = (floatx4){0.f, 0.f, 0.f, 0.f};

    // B prefetch: depth 4 windows, 2 float4 each
    floatx4 vr[4][2];
    #pragma unroll
    for (int u = 0; u < 4; ++u) {
        vr[u][0] = *(const floatx4*)(vrow + u * 32);
        vr[u][1] = *(const floatx4*)(vrow + u * 32 + 4);
    }
    // bits double-buffer: one uint4 (4 windows) per n-tile row
    uint4 bwA[7], bwB[7];
    #pragma unroll
    for (int mt = 0; mt < 7; ++mt)
        bwA[mt] = *(const uint4*)(brow + (size_t)mt * 16 * WPB);

    auto GROUP = [&](int g, uint4 (&bw)[7], uint4 (&bwn)[7]) {
        if (g < 7) {
            #pragma unroll
            for (int mt = 0; mt < 7; ++mt)
                bwn[mt] = *(const uint4*)(brow + (size_t)mt * 16 * WPB + (g + 1) * 4);
        }
        #pragma unroll
        for (int u = 0; u < 4; ++u) {
            const int w = g * 4 + u;
            // ---- B fragment: 8 fp32 -> 8 bf16 (RNE)
            union { short8 s8; uint4 u4; } bq;
            bq.u4.x = pack2(vr[u][0].x, vr[u][0].y);
            bq.u4.y = pack2(vr[u][0].z, vr[u][0].w);
            bq.u4.z = pack2(vr[u][1].x, vr[u][1].y);
            bq.u4.w = pack2(vr[u][1].z, vr[u][1].w);
            // ---- issue B loads for window w+4
            if (g < 7) {
                vr[u][0] = *(const floatx4*)(vrow + (w + 4) * 32);
                vr[u][1] = *(const floatx4*)(vrow + (w + 4) * 32 + 4);
            }
            // ---- A expand + MFMA per n-tile
            #pragma unroll
            for (int mt = 0; mt < 7; ++mt) {
                const unsigned word = (u == 0) ? bw[mt].x : (u == 1) ? bw[mt].y
                                    : (u == 2) ? bw[mt].z : bw[mt].w;
                // frag element j <-> bit (j&3)*8 + lk*2 + (j>>2)
                const unsigned te = (word >> lk2) & 0x01010101u;        // bits lk2+{0,8,16,24}
                const unsigned to = (word >> (lk2 + 1)) & 0x01010101u;  // bits lk2+1+{0,8,16,24}
                union { short8 s8; uint4 u4; } aq;
                // spread bytes {0,1}->halves, {2,3}->halves; *0x3F80 makes bf16 1.0
                aq.u4.x = __umul24(__builtin_amdgcn_perm(0u, te, 0x04010400u), 0x3F80u);
                aq.u4.y = __umul24(__builtin_amdgcn_perm(0u, te, 0x04030402u), 0x3F80u);
                aq.u4.z = __umul24(__builtin_amdgcn_perm(0u, to, 0x04010400u), 0x3F80u);
                aq.u4.w = __umul24(__builtin_amdgcn_perm(0u, to, 0x04030402u), 0x3F80u);
                acc[mt] = __builtin_amdgcn_mfma_f32_16x16x32_bf16(aq.s8, bq.s8, acc[mt], 0, 0, 0);
            }
        }
    };

    for (int gp = 0; gp < 4; ++gp) {
        GROUP(2 * gp,     bwA, bwB);
        GROUP(2 * gp + 1, bwB, bwA);
    }

    // ---- write partials: C/D layout col=l15 (c within tile), row=lk*4+i (n)
    if (USE_PART) {
        float* dst = part + (size_t)gw * (cN * 16);
        #pragma unroll
        for (int mt = 0; mt < 7; ++mt) {
            #pragma unroll
            for (int i = 0; i < 4; ++i) {
                const int n = mt * 16 + lk * 4 + i;
                if (n < cN) dst[n * 16 + l15] = acc[mt][i];
            }
        }
    } else {
        #pragma unroll
        for (int mt = 0; mt < 7; ++mt) {
            #pragma unroll
            for (int i = 0; i < 4; ++i) {
                const int n = mt * 16 + lk * 4 + i;
                if (n < cN)
                    atomicAdd(&pooled[((size_t)b * cN + n) * cC + ct * 16 + l15], acc[mt][i]);
            }
        }
    }
}

// ---------------------------------------------------------------------------
// K2: reduce partials + per (b,n) row -> normalize, sims, CE.
// grid = exactly 200 blocks x 256 threads (4 rows/block). Writes per-block
// (ce_sum, cnt) to bpart[blk*2..] non-atomically (all blocks write -> no init).
// ---------------------------------------------------------------------------
__device__ __forceinline__ float wred(float v) {
    #pragma unroll
    for (int off = 32; off > 0; off >>= 1) v += __shfl_xor(v, off, 64);
    return v;
}

template<bool USE_PART>
__global__ __launch_bounds__(256)
void finalize_kernel(const float* __restrict__ pp, const unsigned* __restrict__ msum,
                     const float* __restrict__ text, const int* __restrict__ labels,
                     const float* __restrict__ temp, float* __restrict__ bpart)
{
    const int lane = threadIdx.x & 63;
    const int wv   = threadIdx.x >> 6;
    const int row  = blockIdx.x * 4 + wv;       // < 800 always (grid exact)
    const int b = row / cN, n = row % cN;

    floatx4 p = (floatx4){0.f, 0.f, 0.f, 0.f};
    if (USE_PART) {
        const int ct  = lane >> 2;
        const int col = (lane & 3) * 4;
        const float* src = pp + ((size_t)(b * 256 + ct * 16)) * (cN * 16) + n * 16 + col;
        #pragma unroll
        for (int kk = 0; kk < KSLICES; ++kk)
            p += *(const floatx4*)(src + (size_t)kk * (cN * 16));
    } else {
        p = *(const floatx4*)(pp + (size_t)row * cC + lane * 4);
    }

    const float m   = (float)msum[row];
    const float inv = 1.0f / fmaxf(m, 1.0f);
    p.x *= inv; p.y *= inv; p.z *= inv; p.w *= inv;

    // c order differs between paths, but all reductions below are c-order-invariant
    const int c_global = USE_PART ? ((lane >> 2) * 16 + (lane & 3) * 4) : lane * 4;

    float psq = p.x * p.x + p.y * p.y + p.z * p.z + p.w * p.w;
    float dot[cT], tsq[cT];
    #pragma unroll
    for (int t = 0; t < cT; ++t) {
        const floatx4 x = *(const floatx4*)(text + (size_t)t * cC + c_global);
        dot[t] = p.x * x.x + p.y * x.y + p.z * x.z + p.w * x.w;
        tsq[t] = x.x * x.x + x.y * x.y + x.z * x.z + x.w * x.w;
    }
    psq = wred(psq);
    #pragma unroll
    for (int t = 0; t < cT; ++t) { dot[t] = wred(dot[t]); tsq[t] = wred(tsq[t]); }

    __shared__ float lce[4], lcnt[4];
    if (lane == 0) {
        const float tempv = fabsf(temp[0]);
        const float pn = fmaxf(sqrtf(psq), 1e-12f);
        float sims[cT], mx = -1e30f;
        #pragma unroll
        for (int t = 0; t < cT; ++t) {
            sims[t] = dot[t] / (pn * fmaxf(sqrtf(tsq[t]), 1e-12f)) / tempv;
            mx = fmaxf(mx, sims[t]);
        }
        float se = 0.f;
        #pragma unroll
        for (int t = 0; t < cT; ++t) se += expf(sims[t] - mx);
        const float lse = logf(se);

        const int lab = labels[row];
        const int tgt = min(max(lab - 1, 0), cT - 1);
        const float ce = -(sims[tgt] - mx - lse);
        const bool valid = (lab >= 1) && (lab <= cT) && (m >= 1.0f);
        lce[wv]  = valid ? ce : 0.f;
        lcnt[wv] = valid ? 1.f : 0.f;
    }
    __syncthreads();
    if (threadIdx.x == 0) {
        bpart[blockIdx.x * 2]     = lce[0] + lce[1] + lce[2] + lce[3];
        bpart[blockIdx.x * 2 + 1] = lcnt[0] + lcnt[1] + lcnt[2] + lcnt[3];
    }
}

// K3: reduce 200 (ce,cnt) pairs -> loss scalar. 1 block x 256 threads.
__global__ __launch_bounds__(256)
void loss_kernel(const float* __restrict__ bp, float* __restrict__ out) {
    const int t = threadIdx.x, lane = t & 63, w = t >> 6;
    float ce = 0.f, cnt = 0.f;
    if (t < 200) { ce = bp[t * 2]; cnt = bp[t * 2 + 1]; }
    ce = wred(ce); cnt = wred(cnt);
    __shared__ float a[8];
    if (lane == 0) { a[w * 2] = ce; a[w * 2 + 1] = cnt; }
    __syncthreads();
    if (t == 0) {
        const float s = a[0] + a[2] + a[4] + a[6];
        const float c = a[1] + a[3] + a[5] + a[7];
        out[0] = (c > 0.f) ? s / fmaxf(c, 1.f) : 0.f;
    }
}

// fallback-path init (avoids hipMemsetAsync in graph)
__global__ void zero_kernel(float* __restrict__ p, int n) {
    const int i = blockIdx.x * 256 + threadIdx.x;
    if (i < n) p[i] = 0.f;
}

// ---------------------------------------------------------------------------
extern "C" void kernel_launch(void* const* d_in, const int* in_sizes, int n_in,
                              void* d_out, int out_size, void* d_ws, size_t ws_size,
                              hipStream_t stream)
{
    const float* vf     = (const float*)d_in[0];
    const float* text   = (const float*)d_in[1];
    const float* masks  = (const float*)d_in[2];
    const int*   labels = (const int*)d_in[3];
    const float* temp   = (const float*)d_in[4];

    float*    wsf   = (float*)d_ws;
    float*    bpart = wsf;                    // 200*2 floats (block partials)
    unsigned* msum  = (unsigned*)(wsf + 512); // 800 u32

    const size_t PART_FLOATS = (size_t)NWAVES * cN * 16;    // 3,276,800 (13.1 MB)
    const size_t BITS_WORDS  = (size_t)cB * NPAD * WPB;     // 458,752  (1.8 MB)

    const bool use_part =
        ws_size >= (4096 + PART_FLOATS + BITS_WORDS + 64) * sizeof(float);

    if (use_part) {
        float*    part = wsf + 4096;
        unsigned* bits = (unsigned*)(wsf + 4096 + PART_FLOATS);
        hipLaunchKernelGGL(mask_prep_kernel, dim3(cB * NPAD), dim3(256), 0, stream,
                           masks, bits, msum);
        hipLaunchKernelGGL((pool_kernel<true>), dim3(NWAVES / 4), dim3(256), 0, stream,
                           vf, bits, part, nullptr);
        hipLaunchKernelGGL((finalize_kernel<true>), dim3(cB * cN / 4), dim3(256), 0, stream,
                           part, msum, text, labels, temp, bpart);
    } else {
        float*    pooled = wsf + 4096;                          // 800*256 fp32
        unsigned* bits   = (unsigned*)(wsf + 4096 + (size_t)cB * cN * cC);
        hipLaunchKernelGGL(zero_kernel, dim3((cB * cN * cC + 255) / 256), dim3(256), 0, stream,
                           pooled, cB * cN * cC);
        hipLaunchKernelGGL(mask_prep_kernel, dim3(cB * NPAD), dim3(256), 0, stream,
                           masks, bits, msum);
        hipLaunchKernelGGL((pool_kernel<false>), dim3(NWAVES / 4), dim3(256), 0, stream,
                           vf, bits, nullptr, pooled);
        hipLaunchKernelGGL((finalize_kernel<false>), dim3(cB * cN / 4), dim3(256), 0, stream,
                           pooled, msum, text, labels, temp, bpart);
    }
    hipLaunchKernelGGL(loss_kernel, dim3(1), dim3(256), 0, stream,
                       bpart, (float*)d_out);
}

// Round 6
// 55.244 us; speedup vs baseline: 2.0206x; 1.0372x over previous
//
#include <hip/hip_runtime.h>
#include <hip/hip_bf16.h>
#include <stdint.h>

// Problem constants (from reference setup_inputs)
constexpr int cB  = 8;
constexpr int cC  = 256;
constexpr int cHW = 128 * 128;   // 16384
constexpr int cN  = 100;
constexpr int cT  = 6;
constexpr int NPAD = 112;        // cN padded to multiple of 16
constexpr int WPB = cHW / 32;    // 512 bit-words per (b,n) row
constexpr int KSLICES = 32;      // k-slices per (b, c-tile)
constexpr int PXS = cHW / KSLICES;   // 512 px per wave
constexpr int NWIN = PXS / 32;       // 16 windows of 32 px
constexpr int NGRP = NWIN / 4;       // 4 groups of 4 windows
constexpr int NBLK = cB * 16 * (KSLICES / 4);  // 1024 blocks (4 ks per block)

typedef __attribute__((ext_vector_type(8))) short short8;
typedef __attribute__((ext_vector_type(4))) float floatx4;

// RNE fp32 pair -> packed bf16x2 (compiler emits v_cvt_pk_bf16_f32 on gfx950)
__device__ __forceinline__ unsigned pack2(float a, float b) {
    const __hip_bfloat16 ha = __float2bfloat16(a);
    const __hip_bfloat16 hb = __float2bfloat16(b);
    return (unsigned)__builtin_bit_cast(unsigned short, ha)
         | ((unsigned)__builtin_bit_cast(unsigned short, hb) << 16);
}

// ---------------------------------------------------------------------------
// K0: binarize masks -> bit-pack [b][n(112)][word(512)] + exact msum per row.
// Bit order within a 32-px word: px offset o = lambda*4 + c <-> bit c*8+lambda
// grid = cB*NPAD blocks x 256 threads (4 waves; wave w owns px [w*4096,+4096))
// ---------------------------------------------------------------------------
__global__ __launch_bounds__(256)
void mask_prep_kernel(const float* __restrict__ masks,
                      unsigned* __restrict__ bits, unsigned* __restrict__ msum)
{
    const int t = threadIdx.x, lane = t & 63, w = t >> 6;
    const int b = blockIdx.x / NPAD;
    const int n = blockIdx.x % NPAD;
    unsigned* dst = bits + ((size_t)b * NPAD + n) * WPB;

    if (n >= cN) {                       // zero pad rows
        *(uint2*)(dst + t * 2) = make_uint2(0u, 0u);
        return;
    }
    const float* src = masks + ((size_t)b * cN + n) * cHW + w * 4096;
    unsigned* wdst = dst + w * 128;
    int pc = 0;
    #pragma unroll
    for (int r = 0; r < 16; ++r) {
        const floatx4 v = *(const floatx4*)(src + r * 256 + lane * 4);
        const bool b0 = v.x > 0.5f, b1 = v.y > 0.5f, b2 = v.z > 0.5f, b3 = v.w > 0.5f;
        const unsigned long long B0 = __ballot(b0), B1 = __ballot(b1),
                                 B2 = __ballot(b2), B3 = __ballot(b3);
        pc += (int)b0 + (int)b1 + (int)b2 + (int)b3;
        if (lane < 8) {
            const int sh = lane * 8;
            const unsigned word =
                  (unsigned)((B0 >> sh) & 0xFFull)
                | ((unsigned)((B1 >> sh) & 0xFFull) << 8)
                | ((unsigned)((B2 >> sh) & 0xFFull) << 16)
                | ((unsigned)((B3 >> sh) & 0xFFull) << 24);
            wdst[r * 8 + lane] = word;
        }
    }
    #pragma unroll
    for (int off = 32; off > 0; off >>= 1) pc += __shfl_xor(pc, off, 64);
    __shared__ int ps[4];
    if (lane == 0) ps[w] = pc;
    __syncthreads();
    if (t == 0) msum[b * cN + n] = (unsigned)(ps[0] + ps[1] + ps[2] + ps[3]);
}

// ---------------------------------------------------------------------------
// K1: pooling via MFMA. 1024 blocks x 4 waves; block owns (b, ct, kg),
// wave widx handles ks = kg*4+widx (512 px). Accumulators are LDS-reduced
// across the 4 waves -> one partial slab per block (6.5 MB total).
// A = mask bits (perm+umul24-expanded to bf16 0/1), B = vf fp32 -> bf16 RNE.
// ---------------------------------------------------------------------------
template<bool USE_PART>
__global__ __launch_bounds__(256)
void pool_kernel(const float* __restrict__ vf, const unsigned* __restrict__ bits,
                 float* __restrict__ part, float* __restrict__ pooled)
{
    __shared__ float red[4][28][64];

    const int tid  = threadIdx.x;
    const int lane = tid & 63;
    const int widx = tid >> 6;
    const int bid  = blockIdx.x;
    const int b    = bid >> 7;
    const int ct   = (bid >> 3) & 15;
    const int kg   = bid & 7;
    const int ks   = kg * 4 + widx;
    const int l15  = lane & 15;
    const int lk   = lane >> 4;          // 0..3
    const int lk2  = lk * 2;             // bit-offset base for expansion
    const int p0   = ks * PXS;

    const float* vrow = vf + ((size_t)(b * cC + ct * 16 + l15)) * cHW + p0 + lk * 8;
    const unsigned* brow = bits + ((size_t)b * NPAD + l15) * WPB + (p0 >> 5);

    floatx4 acc[7];
    #pragma unroll
    for (int mt = 0; mt < 7; ++mt) acc[mt] = (floatx4){0.f, 0.f, 0.f, 0.f};

    // B prefetch: depth 4 windows, 2 float4 each
    floatx4 vr[4][2];
    #pragma unroll
    for (int u = 0; u < 4; ++u) {
        vr[u][0] = *(const floatx4*)(vrow + u * 32);
        vr[u][1] = *(const floatx4*)(vrow + u * 32 + 4);
    }
    // bits double-buffer: one uint4 (4 windows) per n-tile row
    uint4 bwA[7], bwB[7];
    #pragma unroll
    for (int mt = 0; mt < 7; ++mt)
        bwA[mt] = *(const uint4*)(brow + (size_t)mt * 16 * WPB);

    auto GROUP = [&](int g, uint4 (&bw)[7], uint4 (&bwn)[7]) {
        if (g < NGRP - 1) {
            #pragma unroll
            for (int mt = 0; mt < 7; ++mt)
                bwn[mt] = *(const uint4*)(brow + (size_t)mt * 16 * WPB + (g + 1) * 4);
        }
        #pragma unroll
        for (int u = 0; u < 4; ++u) {
            const int w = g * 4 + u;
            // ---- B fragment: 8 fp32 -> 8 bf16 (RNE)
            union { short8 s8; uint4 u4; } bq;
            bq.u4.x = pack2(vr[u][0].x, vr[u][0].y);
            bq.u4.y = pack2(vr[u][0].z, vr[u][0].w);
            bq.u4.z = pack2(vr[u][1].x, vr[u][1].y);
            bq.u4.w = pack2(vr[u][1].z, vr[u][1].w);
            // ---- issue B loads for window w+4
            if (g < NGRP - 1) {
                vr[u][0] = *(const floatx4*)(vrow + (w + 4) * 32);
                vr[u][1] = *(const floatx4*)(vrow + (w + 4) * 32 + 4);
            }
            // ---- A expand + MFMA per n-tile
            #pragma unroll
            for (int mt = 0; mt < 7; ++mt) {
                const unsigned word = (u == 0) ? bw[mt].x : (u == 1) ? bw[mt].y
                                    : (u == 2) ? bw[mt].z : bw[mt].w;
                // frag element j <-> bit (j&3)*8 + lk*2 + (j>>2)
                const unsigned te = (word >> lk2) & 0x01010101u;
                const unsigned to = (word >> (lk2 + 1)) & 0x01010101u;
                union { short8 s8; uint4 u4; } aq;
                aq.u4.x = __umul24(__builtin_amdgcn_perm(0u, te, 0x04010400u), 0x3F80u);
                aq.u4.y = __umul24(__builtin_amdgcn_perm(0u, te, 0x04030402u), 0x3F80u);
                aq.u4.z = __umul24(__builtin_amdgcn_perm(0u, to, 0x04010400u), 0x3F80u);
                aq.u4.w = __umul24(__builtin_amdgcn_perm(0u, to, 0x04030402u), 0x3F80u);
                acc[mt] = __builtin_amdgcn_mfma_f32_16x16x32_bf16(aq.s8, bq.s8, acc[mt], 0, 0, 0);
            }
        }
    };

    GROUP(0, bwA, bwB);
    GROUP(1, bwB, bwA);
    GROUP(2, bwA, bwB);
    GROUP(3, bwB, bwA);

    // ---- LDS reduce across the 4 waves (4 k-slices of same (b,ct))
    #pragma unroll
    for (int mt = 0; mt < 7; ++mt)
        #pragma unroll
        for (int i = 0; i < 4; ++i)
            red[widx][mt * 4 + i][lane] = acc[mt][i];
    __syncthreads();

    // thread (lane, wq=widx) reduces elems e = mt*4 + wq  ->  n = mt*16+(lane>>4)*4+wq
    float s[7];
    #pragma unroll
    for (int mt = 0; mt < 7; ++mt) {
        const int e = mt * 4 + widx;
        s[mt] = red[0][e][lane] + red[1][e][lane] + red[2][e][lane] + red[3][e][lane];
    }

    if (USE_PART) {
        float* dst = part + (size_t)bid * (cN * 16);
        #pragma unroll
        for (int mt = 0; mt < 7; ++mt) {
            const int n = mt * 16 + (lane >> 4) * 4 + widx;
            if (n < cN) dst[n * 16 + l15] = s[mt];
        }
    } else {
        #pragma unroll
        for (int mt = 0; mt < 7; ++mt) {
            const int n = mt * 16 + (lane >> 4) * 4 + widx;
            if (n < cN)
                atomicAdd(&pooled[((size_t)b * cN + n) * cC + ct * 16 + l15], s[mt]);
        }
    }
}

// ---------------------------------------------------------------------------
// K2: reduce partials + per (b,n) row -> normalize, sims, CE.
// grid = exactly 200 blocks x 256 threads (4 rows/block). Writes per-block
// (ce_sum, cnt) to bpart[blk*2..] non-atomically (all blocks write -> no init).
// ---------------------------------------------------------------------------
__device__ __forceinline__ float wred(float v) {
    #pragma unroll
    for (int off = 32; off > 0; off >>= 1) v += __shfl_xor(v, off, 64);
    return v;
}

template<bool USE_PART>
__global__ __launch_bounds__(256)
void finalize_kernel(const float* __restrict__ pp, const unsigned* __restrict__ msum,
                     const float* __restrict__ text, const int* __restrict__ labels,
                     const float* __restrict__ temp, float* __restrict__ bpart)
{
    const int lane = threadIdx.x & 63;
    const int wv   = threadIdx.x >> 6;
    const int row  = blockIdx.x * 4 + wv;       // < 800 always (grid exact)
    const int b = row / cN, n = row % cN;

    floatx4 p = (floatx4){0.f, 0.f, 0.f, 0.f};
    if (USE_PART) {
        const int ct  = lane >> 2;
        const int col = (lane & 3) * 4;
        // part[(b*16+ct)*8 + kg][n][col..]
        const float* src = pp + ((size_t)(b * 16 + ct) * 8) * (cN * 16) + n * 16 + col;
        #pragma unroll
        for (int kg = 0; kg < 8; ++kg)
            p += *(const floatx4*)(src + (size_t)kg * (cN * 16));
    } else {
        p = *(const floatx4*)(pp + (size_t)row * cC + lane * 4);
    }

    const float m   = (float)msum[row];
    const float inv = 1.0f / fmaxf(m, 1.0f);
    p.x *= inv; p.y *= inv; p.z *= inv; p.w *= inv;

    // c order differs between paths, but all reductions below are c-order-invariant
    const int c_global = USE_PART ? ((lane >> 2) * 16 + (lane & 3) * 4) : lane * 4;

    float psq = p.x * p.x + p.y * p.y + p.z * p.z + p.w * p.w;
    float dot[cT], tsq[cT];
    #pragma unroll
    for (int t = 0; t < cT; ++t) {
        const floatx4 x = *(const floatx4*)(text + (size_t)t * cC + c_global);
        dot[t] = p.x * x.x + p.y * x.y + p.z * x.z + p.w * x.w;
        tsq[t] = x.x * x.x + x.y * x.y + x.z * x.z + x.w * x.w;
    }
    psq = wred(psq);
    #pragma unroll
    for (int t = 0; t < cT; ++t) { dot[t] = wred(dot[t]); tsq[t] = wred(tsq[t]); }

    __shared__ float lce[4], lcnt[4];
    if (lane == 0) {
        const float tempv = fabsf(temp[0]);
        const float pn = fmaxf(sqrtf(psq), 1e-12f);
        float sims[cT], mx = -1e30f;
        #pragma unroll
        for (int t = 0; t < cT; ++t) {
            sims[t] = dot[t] / (pn * fmaxf(sqrtf(tsq[t]), 1e-12f)) / tempv;
            mx = fmaxf(mx, sims[t]);
        }
        float se = 0.f;
        #pragma unroll
        for (int t = 0; t < cT; ++t) se += expf(sims[t] - mx);
        const float lse = logf(se);

        const int lab = labels[row];
        const int tgt = min(max(lab - 1, 0), cT - 1);
        const float ce = -(sims[tgt] - mx - lse);
        const bool valid = (lab >= 1) && (lab <= cT) && (m >= 1.0f);
        lce[wv]  = valid ? ce : 0.f;
        lcnt[wv] = valid ? 1.f : 0.f;
    }
    __syncthreads();
    if (threadIdx.x == 0) {
        bpart[blockIdx.x * 2]     = lce[0] + lce[1] + lce[2] + lce[3];
        bpart[blockIdx.x * 2 + 1] = lcnt[0] + lcnt[1] + lcnt[2] + lcnt[3];
    }
}

// K3: reduce 200 (ce,cnt) pairs -> loss scalar. 1 block x 256 threads.
__global__ __launch_bounds__(256)
void loss_kernel(const float* __restrict__ bp, float* __restrict__ out) {
    const int t = threadIdx.x, lane = t & 63, w = t >> 6;
    float ce = 0.f, cnt = 0.f;
    if (t < 200) { ce = bp[t * 2]; cnt = bp[t * 2 + 1]; }
    ce = wred(ce); cnt = wred(cnt);
    __shared__ float a[8];
    if (lane == 0) { a[w * 2] = ce; a[w * 2 + 1] = cnt; }
    __syncthreads();
    if (t == 0) {
        const float s = a[0] + a[2] + a[4] + a[6];
        const float c = a[1] + a[3] + a[5] + a[7];
        out[0] = (c > 0.f) ? s / fmaxf(c, 1.f) : 0.f;
    }
}

// fallback-path init (avoids hipMemsetAsync in graph)
__global__ void zero_kernel(float* __restrict__ p, int n) {
    const int i = blockIdx.x * 256 + threadIdx.x;
    if (i < n) p[i] = 0.f;
}

// ---------------------------------------------------------------------------
extern "C" void kernel_launch(void* const* d_in, const int* in_sizes, int n_in,
                              void* d_out, int out_size, void* d_ws, size_t ws_size,
                              hipStream_t stream)
{
    const float* vf     = (const float*)d_in[0];
    const float* text   = (const float*)d_in[1];
    const float* masks  = (const float*)d_in[2];
    const int*   labels = (const int*)d_in[3];
    const float* temp   = (const float*)d_in[4];

    float*    wsf   = (float*)d_ws;
    float*    bpart = wsf;                    // 200*2 floats (block partials)
    unsigned* msum  = (unsigned*)(wsf + 512); // 800 u32

    const size_t PART_FLOATS = (size_t)NBLK * cN * 16;      // 1,638,400 (6.55 MB)
    const size_t BITS_WORDS  = (size_t)cB * NPAD * WPB;     // 458,752  (1.8 MB)

    const bool use_part =
        ws_size >= (4096 + PART_FLOATS + BITS_WORDS + 64) * sizeof(float);

    if (use_part) {
        float*    part = wsf + 4096;
        unsigned* bits = (unsigned*)(wsf + 4096 + PART_FLOATS);
        hipLaunchKernelGGL(mask_prep_kernel, dim3(cB * NPAD), dim3(256), 0, stream,
                           masks, bits, msum);
        hipLaunchKernelGGL((pool_kernel<true>), dim3(NBLK), dim3(256), 0, stream,
                           vf, bits, part, nullptr);
        hipLaunchKernelGGL((finalize_kernel<true>), dim3(cB * cN / 4), dim3(256), 0, stream,
                           part, msum, text, labels, temp, bpart);
    } else {
        float*    pooled = wsf + 4096;                          // 800*256 fp32
        unsigned* bits   = (unsigned*)(wsf + 4096 + (size_t)cB * cN * cC);
        hipLaunchKernelGGL(zero_kernel, dim3((cB * cN * cC + 255) / 256), dim3(256), 0, stream,
                           pooled, cB * cN * cC);
        hipLaunchKernelGGL(mask_prep_kernel, dim3(cB * NPAD), dim3(256), 0, stream,
                           masks, bits, msum);
        hipLaunchKernelGGL((pool_kernel<false>), dim3(NBLK), dim3(256), 0, stream,
                           vf, bits, nullptr, pooled);
        hipLaunchKernelGGL((finalize_kernel<false>), dim3(cB * cN / 4), dim3(256), 0, stream,
                           pooled, msum, text, labels, temp, bpart);
    }
    hipLaunchKernelGGL(loss_kernel, dim3(1), dim3(256), 0, stream,
                       bpart, (float*)d_out);
}